// Round 8
// baseline (193.310 us; speedup 1.0000x reference)
//
#include <hip/hip_runtime.h>
#include <hip/hip_bf16.h>
#include <math.h>

#define BB 64
#define LL 1024
#define EE 256
#define KK 8

typedef __attribute__((ext_vector_type(8))) short  bfrag;   // 8 bf16 (4 VGPRs)
typedef __attribute__((ext_vector_type(4))) short  short4v; // 4 bf16 (8B)
typedef __attribute__((ext_vector_type(4))) float  f32x4;

// Maug tiled: per kb (8): 320 rows x 32 k shorts (rows 272..319 pad) = 10240 shorts
#define MT_KB 10240

// workspace layout (units: floats)
#define O_MHI    ((size_t)0)                    // 8*10240 shorts = 40960 floats
#define O_MLO    ((size_t)40960)                // 40960
#define O_BVAUG  ((size_t)81920)                // 16 floats
#define O_X      ((size_t)81984)                // 16777216: ThiT+TloT (gemm), then St (fft)
#define O_KPT    (O_X + (size_t)16777216)       // B*E*L ([b][e][l])
#define O_VSUB   (O_KPT + (size_t)16777216)     // B*L*16 = 1048576
#define O_MV     (O_VSUB + (size_t)1048576)     // B*L = 65536
#define O_STATS  (O_MV + (size_t)65536)
// xcorr partials (513 float2 per (b, e-pair)) overlay the head of each wave's own
// 2-channel St slab (2048 floats >= 1026) — fully consumed by that wave first.

__device__ __forceinline__ float2 cmulf(float2 a, float2 b) {
    return make_float2(a.x * b.x - a.y * b.y, a.x * b.y + a.y * b.x);
}

__device__ __forceinline__ int PHY(int i) { return i + (i >> 4); }  // LDS pad (ifft only)

__device__ __forceinline__ void splitbf(float x, unsigned short& h, unsigned short& l) {
    __hip_bfloat16 hb = __float2bfloat16(x);
    float hf = __bfloat162float(hb);
    __hip_bfloat16 lb = __float2bfloat16(x - hf);
    h = *(unsigned short*)&hb;
    l = *(unsigned short*)&lb;
}

__device__ __forceinline__ void gload16(const unsigned short* g, unsigned short* l) {
    __builtin_amdgcn_global_load_lds(
        (const __attribute__((address_space(1))) unsigned int*)g,
        (__attribute__((address_space(3))) unsigned int*)l, 16, 0, 0);
}

__device__ __forceinline__ int slot_of(int r, int kq) { return (kq + (r >> 1)) & 3; }

// ---------------- kernel 1: Maug = [Wq^T Wk ; Wv rows 0..7,248..255], bf16 hi/lo, tiled+swizzled
__global__ __launch_bounds__(256) void build_maug(
    const float* __restrict__ Wq, const float* __restrict__ Wk,
    const float* __restrict__ Wv, const float* __restrict__ bv,
    unsigned short* __restrict__ mhiT, unsigned short* __restrict__ mloT,
    float* __restrict__ bvaug) {
    int n = blockIdx.x;   // 0..271
    int j = threadIdx.x;  // k: 0..255
    float acc;
    if (n < EE) {
        acc = 0.f;
        for (int e = 0; e < EE; ++e)
            acc += Wq[e * EE + n] * Wk[e * EE + j];
    } else {
        int t = n - EE;
        int c = (t < 8) ? t : (240 + t);
        acc = Wv[c * EE + j];
    }
    unsigned short h, l;
    splitbf(acc, h, l);
    const int kb = j >> 5, kq = (j >> 3) & 3;
    const size_t dst = (size_t)kb * MT_KB + n * 32 + slot_of(n, kq) * 8 + (j & 7);
    mhiT[dst] = h;
    mloT[dst] = l;
    if (n == 0 && j < 16) bvaug[j] = bv[(j < 8) ? j : (240 + j)];
}

// ---------------- kernel 1c: split T -> bf16 hi/lo in tiled+swizzled layout
__global__ __launch_bounds__(256) void split_T(
    const float* __restrict__ T,
    unsigned short* __restrict__ thiT, unsigned short* __restrict__ tloT) {
    const size_t g = (size_t)blockIdx.x * 256 + threadIdx.x;
    const size_t i = g * 8;
    const int s = (int)(i >> 8), k = (int)(i & 255);
    const int kb = k >> 5, kq = (k >> 3) & 3;
    const int st = s >> 6, row = s & 63;
    f32x4 v0 = *(const f32x4*)&T[i];
    f32x4 v1 = *(const f32x4*)&T[i + 4];
    short4v h0, l0, h1, l1;
#pragma unroll
    for (int j = 0; j < 4; ++j) {
        unsigned short h, l;
        splitbf(v0[j], h, l); h0[j] = (short)h; l0[j] = (short)l;
        splitbf(v1[j], h, l); h1[j] = (short)h; l1[j] = (short)l;
    }
    const size_t dst = ((size_t)(st * 8 + kb)) * 2048 + row * 32 + slot_of(row, kq) * 8;
    *(short4v*)&thiT[dst] = h0; *(short4v*)&thiT[dst + 4] = h1;
    *(short4v*)&tloT[dst] = l0; *(short4v*)&tloT[dst + 4] = l1;
}

// ---------------- kernel 1b: St[b][e][l] = S[b][l][e]
__global__ __launch_bounds__(256) void transpose_S(
    const float* __restrict__ S, float* __restrict__ St) {
    __shared__ float tile[32][33];
    const int b = blockIdx.z;
    const int l0 = blockIdx.x * 32, e0 = blockIdx.y * 32;
    const int tx = threadIdx.x & 31, ty = threadIdx.x >> 5;
#pragma unroll
    for (int i = 0; i < 32; i += 8)
        tile[ty + i][tx] = S[((size_t)b * LL + l0 + ty + i) * EE + e0 + tx];
    __syncthreads();
#pragma unroll
    for (int i = 0; i < 32; i += 8)
        St[((size_t)b * EE + e0 + ty + i) * LL + l0 + tx] = tile[tx][ty + i];
}

// ---------------- kernel 2: MFMA GEMM (unchanged from R7)
__global__ __launch_bounds__(256, 3) void gemm_mfma(
    const unsigned short* __restrict__ thiT, const unsigned short* __restrict__ tloT,
    const unsigned short* __restrict__ mhiT, const unsigned short* __restrict__ mloT,
    const float* __restrict__ bvaug,
    float* __restrict__ kp_t, float* __restrict__ vsub) {
    __shared__ alignas(16) unsigned short Ah[2048];
    __shared__ alignas(16) unsigned short Al[2048];
    __shared__ alignas(16) unsigned short Bh[10240];
    __shared__ alignas(16) unsigned short Bl[10240];
    const int tid = threadIdx.x;
    const int w = tid >> 6, lane = tid & 63;
    const int lrow = lane & 15, lk = lane >> 4;
    const int st = blockIdx.x;
    const size_t s0 = (size_t)st * 64;
    const int bb = (int)(s0 >> 10), l0 = (int)(s0 & 1023);
    const int gl = w * 64 + lane;

    f32x4 acc[4][4];
    f32x4 acc2[4];
#pragma unroll
    for (int m = 0; m < 4; ++m) {
#pragma unroll
        for (int c = 0; c < 4; ++c) acc[m][c] = (f32x4){0.f, 0.f, 0.f, 0.f};
        acc2[m] = (f32x4){0.f, 0.f, 0.f, 0.f};
    }

    for (int kb = 0; kb < 8; ++kb) {
        __syncthreads();
        const unsigned short* asrcH = thiT + ((size_t)(st * 8 + kb)) * 2048;
        const unsigned short* asrcL = tloT + ((size_t)(st * 8 + kb)) * 2048;
        gload16(asrcH + gl * 8, &Ah[(size_t)w * 512]);
        gload16(asrcL + gl * 8, &Al[(size_t)w * 512]);
        const unsigned short* bsrcH = mhiT + (size_t)kb * MT_KB;
        const unsigned short* bsrcL = mloT + (size_t)kb * MT_KB;
#pragma unroll
        for (int q = 0; q < 5; ++q)
            gload16(bsrcH + q * 2048 + gl * 8, &Bh[q * 2048 + w * 512]);
#pragma unroll
        for (int q = 0; q < 5; ++q)
            gload16(bsrcL + q * 2048 + gl * 8, &Bl[q * 2048 + w * 512]);
        __syncthreads();

        bfrag ah[4], al[4];
#pragma unroll
        for (int m = 0; m < 4; ++m) {
            const int row = m * 16 + lrow;
            const int off = row * 32 + slot_of(row, lk) * 8;
            ah[m] = *(const bfrag*)&Ah[off];
            al[m] = *(const bfrag*)&Al[off];
        }
#pragma unroll
        for (int c = 0; c < 4; ++c) {
            const int n = w * 64 + c * 16 + lrow;
            const int off = n * 32 + slot_of(n, lk) * 8;
            bfrag bh = *(const bfrag*)&Bh[off];
            bfrag bl = *(const bfrag*)&Bl[off];
#pragma unroll
            for (int m = 0; m < 4; ++m) {
                acc[m][c] = __builtin_amdgcn_mfma_f32_16x16x32_bf16(ah[m], bh, acc[m][c], 0, 0, 0);
                acc[m][c] = __builtin_amdgcn_mfma_f32_16x16x32_bf16(ah[m], bl, acc[m][c], 0, 0, 0);
                acc[m][c] = __builtin_amdgcn_mfma_f32_16x16x32_bf16(al[m], bh, acc[m][c], 0, 0, 0);
            }
        }
        if (w == 0) {
            const int n = EE + lrow;
            const int off = n * 32 + slot_of(n, lk) * 8;
            bfrag bh = *(const bfrag*)&Bh[off];
            bfrag bl = *(const bfrag*)&Bl[off];
#pragma unroll
            for (int m = 0; m < 4; ++m) {
                acc2[m] = __builtin_amdgcn_mfma_f32_16x16x32_bf16(ah[m], bh, acc2[m], 0, 0, 0);
                acc2[m] = __builtin_amdgcn_mfma_f32_16x16x32_bf16(ah[m], bl, acc2[m], 0, 0, 0);
                acc2[m] = __builtin_amdgcn_mfma_f32_16x16x32_bf16(al[m], bh, acc2[m], 0, 0, 0);
            }
        }
    }
#pragma unroll
    for (int m = 0; m < 4; ++m) {
        const int srow = m * 16 + lk * 4;
#pragma unroll
        for (int c = 0; c < 4; ++c) {
            const int n = w * 64 + c * 16 + lrow;
            *(f32x4*)&kp_t[((size_t)(bb * EE + n)) * LL + l0 + srow] = acc[m][c];
        }
    }
    if (w == 0) {
        const float bvv = bvaug[lrow];
#pragma unroll
        for (int m = 0; m < 4; ++m) {
            const int srow = m * 16 + lk * 4;
#pragma unroll
            for (int j = 0; j < 4; ++j)
                vsub[(s0 + srow + j) * 16 + lrow] = acc2[m][j] + bvv;
        }
    }
}

// ============ kernel 3: register/shuffle FFT xcorr — no LDS, no barriers ============
// One wave per 2 e-channels. 1024 = 16(reg slots) x 64(lanes) six-step FFT.
// Lane l holds x[l+64r]; after FFT, slot k1 of lane l holds X[k1 + 16*bitrev6(l)].
#define W16_1R 0.923879532511286756f
#define W16_1I (-0.382683432365089772f)
#define W16_2R 0.707106781186547524f
#define W16_2I (-0.707106781186547524f)
#define W16_3R 0.382683432365089772f
#define W16_3I (-0.923879532511286756f)
#define W16_4R 0.f
#define W16_4I (-1.f)
#define W16_6R (-0.707106781186547524f)
#define W16_6I (-0.707106781186547524f)
#define W16_9R (-0.923879532511286756f)
#define W16_9I 0.382683432365089772f

__global__ __launch_bounds__(256) void xcorr_kernel(
    float* __restrict__ St, const float* __restrict__ kp_t) {
    const int lane = threadIdx.x & 63;
    const int wv = threadIdx.x >> 6;
    const int b = blockIdx.x >> 5;            // 32 chunk-blocks per b
    const int c8 = blockIdx.x & 31;           // chunk of 8 e-channels
    const int e0 = c8 * 8 + 2 * wv;           // this wave: e0, e0+1

    const int lrev = (int)(__brev((unsigned)lane) >> 26);           // bitrev6(lane)
    const int l0p = (int)(__brev((unsigned)((64 - lrev) & 63)) >> 26); // slot-0 partner lane

    // per-lane FFT64 stage constants: g (+1/-1), effective twiddle we (w or 1)
    const int msk[6] = {32, 16, 8, 4, 2, 1};
    float gsg[6], wer[6], wei[6];
#pragma unroll
    for (int s = 0; s < 6; ++s) {
        const int m = msk[s];
        const int hi = lane & m;
        gsg[s] = hi ? -1.f : 1.f;
        if (hi) {
            float ang = -3.14159265358979323846f * (float)(lane & (m - 1)) / (float)m;
            float sv, cv; __sincosf(ang, &sv, &cv);
            wer[s] = cv; wei[s] = sv;
        } else { wer[s] = 1.f; wei[s] = 0.f; }
    }
    // w1l = exp(-2*pi*i*lane/1024)
    float w1r, w1i;
    { float sv, cv; __sincosf(-2.f * 3.14159265358979323846f * (float)lane / 1024.f, &sv, &cv);
      w1r = cv; w1i = sv; }

    float pr[16], pi[16];
#pragma unroll
    for (int k = 0; k < 16; ++k) { pr[k] = 0.f; pi[k] = 0.f; }

    const size_t base = ((size_t)b * EE + e0) * LL;
    for (int ec = 0; ec < 2; ++ec) {
        const float* sp = St + base + (size_t)ec * LL;
        const float* kp = kp_t + base + (size_t)ec * LL;
        float yr[16], yi[16];
        // ---- load: z = s + i*kp, element l + 64r
#pragma unroll
        for (int r = 0; r < 16; ++r) {
            yr[r] = sp[lane + 64 * r];
            yi[r] = kp[lane + 64 * r];
        }
        // ---- FFT16 over slots (forward, w = e^{-2pi i/16}); out natural k1
        {
            float zr[16], zi[16];
#pragma unroll
            for (int r = 0; r < 4; ++r) {
                float t0r = yr[r] + yr[r + 8],  t0i = yi[r] + yi[r + 8];
                float t1r = yr[r] - yr[r + 8],  t1i = yi[r] - yi[r + 8];
                float t2r = yr[r + 4] + yr[r + 12], t2i = yi[r + 4] + yi[r + 12];
                float t3r = yr[r + 4] - yr[r + 12], t3i = yi[r + 4] - yi[r + 12];
                // B0..B3 (w4 = -i): B1 = t1 - i*t3, B3 = t1 + i*t3
                float B0r = t0r + t2r, B0i = t0i + t2i;
                float B1r = t1r + t3i, B1i = t1i - t3r;
                float B2r = t0r - t2r, B2i = t0i - t2i;
                float B3r = t1r - t3i, B3i = t1i + t3r;
                zr[r] = B0r; zi[r] = B0i;
                // z[4p+r] = Bp * w16^{p*r}
                if (r == 0) {
                    zr[4] = B1r; zi[4] = B1i;
                    zr[8] = B2r; zi[8] = B2i;
                    zr[12] = B3r; zi[12] = B3i;
                } else if (r == 1) {
                    zr[5] = B1r * W16_1R - B1i * W16_1I; zi[5] = B1r * W16_1I + B1i * W16_1R;
                    zr[9] = B2r * W16_2R - B2i * W16_2I; zi[9] = B2r * W16_2I + B2i * W16_2R;
                    zr[13] = B3r * W16_3R - B3i * W16_3I; zi[13] = B3r * W16_3I + B3i * W16_3R;
                } else if (r == 2) {
                    zr[6] = B1r * W16_2R - B1i * W16_2I; zi[6] = B1r * W16_2I + B1i * W16_2R;
                    zr[10] = B2r * W16_4R - B2i * W16_4I; zi[10] = B2r * W16_4I + B2i * W16_4R;
                    zr[14] = B3r * W16_6R - B3i * W16_6I; zi[14] = B3r * W16_6I + B3i * W16_6R;
                } else {
                    zr[7] = B1r * W16_3R - B1i * W16_3I; zi[7] = B1r * W16_3I + B1i * W16_3R;
                    zr[11] = B2r * W16_6R - B2i * W16_6I; zi[11] = B2r * W16_6I + B2i * W16_6R;
                    zr[15] = B3r * W16_9R - B3i * W16_9I; zi[15] = B3r * W16_9I + B3i * W16_9R;
                }
            }
#pragma unroll
            for (int p = 0; p < 4; ++p) {
                float u0r = zr[4 * p] + zr[4 * p + 2], u0i = zi[4 * p] + zi[4 * p + 2];
                float u1r = zr[4 * p] - zr[4 * p + 2], u1i = zi[4 * p] - zi[4 * p + 2];
                float u2r = zr[4 * p + 1] + zr[4 * p + 3], u2i = zi[4 * p + 1] + zi[4 * p + 3];
                float u3r = zr[4 * p + 1] - zr[4 * p + 3], u3i = zi[4 * p + 1] - zi[4 * p + 3];
                yr[p] = u0r + u2r;       yi[p] = u0i + u2i;
                yr[4 + p] = u1r + u3i;   yi[4 + p] = u1i - u3r;
                yr[8 + p] = u0r - u2r;   yi[8 + p] = u0i - u2i;
                yr[12 + p] = u1r - u3i;  yi[12 + p] = u1i + u3r;
            }
        }
        // ---- inter-factor twiddle: y[k1] *= w1l^{k1} (recurrence)
        {
            float cr = w1r, ci = w1i;
#pragma unroll
            for (int k = 1; k < 16; ++k) {
                float tr = yr[k] * cr - yi[k] * ci;
                yi[k] = yr[k] * ci + yi[k] * cr;
                yr[k] = tr;
                if (k < 15) {
                    float nr = cr * w1r - ci * w1i;
                    ci = cr * w1i + ci * w1r;
                    cr = nr;
                }
            }
        }
        // ---- FFT64 across lanes (DIF radix-2, 6 shuffle stages), per slot
#pragma unroll
        for (int k = 0; k < 16; ++k) {
            float re = yr[k], im = yi[k];
#pragma unroll
            for (int s = 0; s < 6; ++s) {
                float orr = __shfl_xor(re, msk[s]);
                float oii = __shfl_xor(im, msk[s]);
                float tr = orr + gsg[s] * re;
                float ti = oii + gsg[s] * im;
                re = tr * wer[s] - ti * wei[s];
                im = tr * wei[s] + ti * wer[s];
            }
            yr[k] = re; yi[k] = im;
        }
        // ---- cross-power accumulate: P[f] = 0.5*Im(A*C) + 0.25i*(|A|^2-|C|^2), C = X[1024-f]
        {
            const int pl = 63 - lane;
            // slot 0: partner is slot 0 at lane l0p
            float cr = __shfl(yr[0], l0p), ci = __shfl(yi[0], l0p);
            pr[0] += 0.5f * (yr[0] * ci + yi[0] * cr);
            pi[0] += 0.25f * ((yr[0] * yr[0] + yi[0] * yi[0]) - (cr * cr + ci * ci));
#pragma unroll
            for (int k = 1; k < 16; ++k) {
                float c2r = __shfl(yr[16 - k], pl), c2i = __shfl(yi[16 - k], pl);
                pr[k] += 0.5f * (yr[k] * c2i + yi[k] * c2r);
                pi[k] += 0.25f * ((yr[k] * yr[k] + yi[k] * yi[k]) - (c2r * c2r + c2i * c2i));
            }
        }
    }
    // ---- store natural-order P[f], f = k1 + 16*lrev <= 512, into own slab head
    float* slab = St + base;
    if (lrev < 32) {
#pragma unroll
        for (int k = 0; k < 16; ++k) {
            const int f = k + 16 * lrev;
            slab[2 * f] = pr[k];
            slab[2 * f + 1] = pi[k];
        }
    }
    if (lane == 1) {          // lrev == 32: f = 512 from slot 0
        slab[1024] = pr[0];
        slab[1025] = pi[0];
    }
}

// ---------------- radix-4 Stockham FFT (LDS), used by ifft only
template<bool INV>
__device__ __forceinline__ void fft1024_r4(float2* a, float2* b,
                                           const float2* __restrict__ tw, int tid) {
    float2* src = a;
    float2* dst = b;
#pragma unroll
    for (int t = 0; t < 5; ++t) {
        const int Ns = 1 << (2 * t);
        const int sh = 8 - 2 * t;
        __syncthreads();
        const int j = tid;
        const int k = j & (Ns - 1);
        float2 w1 = tw[k << sh];
        float2 w2 = tw[k << (sh + 1)];
        float2 w3 = cmulf(w1, w2);
        if (INV) { w1.y = -w1.y; w2.y = -w2.y; w3.y = -w3.y; }
        float2 a0 = src[PHY(j)];
        float2 a1 = cmulf(w1, src[PHY(j + 256)]);
        float2 a2 = cmulf(w2, src[PHY(j + 512)]);
        float2 a3 = cmulf(w3, src[PHY(j + 768)]);
        float2 t0 = make_float2(a0.x + a2.x, a0.y + a2.y);
        float2 t1 = make_float2(a0.x - a2.x, a0.y - a2.y);
        float2 t2 = make_float2(a1.x + a3.x, a1.y + a3.y);
        float2 t3 = make_float2(a1.x - a3.x, a1.y - a3.y);
        float2 u3 = INV ? make_float2(-t3.y, t3.x) : make_float2(t3.y, -t3.x);
        const int base = ((j >> (2 * t)) << (2 * t + 2)) + k;
        dst[PHY(base)]          = make_float2(t0.x + t2.x, t0.y + t2.y);
        dst[PHY(base + Ns)]     = make_float2(t1.x + u3.x, t1.y + u3.y);
        dst[PHY(base + 2 * Ns)] = make_float2(t0.x - t2.x, t0.y - t2.y);
        dst[PHY(base + 3 * Ns)] = make_float2(t1.x - u3.x, t1.y - u3.y);
        float2* tmp = src; src = dst; dst = tmp;
    }
    __syncthreads();
}

// ---------------- kernel 4: per b: reduce 128 partials, Hermitian irfft -> mean_value
__global__ __launch_bounds__(256) void ifft_kernel(
    const float* __restrict__ St, float* __restrict__ mv) {
    __shared__ float2 bufA[1088];
    __shared__ float2 bufB[1088];
    __shared__ float2 tw[512];
    const int tid = threadIdx.x;
    const int b = blockIdx.x;
    for (int m = tid; m < 512; m += 256) {
        float sv, cv;
        sincosf(-2.f * 3.14159265358979323846f * (float)m / 1024.f, &sv, &cv);
        tw[m] = make_float2(cv, sv);
    }
#pragma unroll
    for (int u = 0; u < 2; ++u) {
        int f = tid + (u << 8);
        float2 s = make_float2(0.f, 0.f);
        for (int c = 0; c < 128; ++c) {
            const float2* pp = (const float2*)&St[((size_t)b * EE + (size_t)c * 2) * LL];
            float2 v = pp[f];
            s.x += v.x; s.y += v.y;
        }
        if (f == 0) s.y = 0.f;
        bufA[PHY(f)] = s;
        if (f > 0) bufA[PHY(1024 - f)] = make_float2(s.x, -s.y);
    }
    if (tid == 0) {
        float sx = 0.f;
        for (int c = 0; c < 128; ++c) {
            const float2* pp = (const float2*)&St[((size_t)b * EE + (size_t)c * 2) * LL];
            sx += pp[512].x;
        }
        bufA[PHY(512)] = make_float2(sx, 0.f);
    }
    fft1024_r4<true>(bufA, bufB, tw, tid);
    const float sc = 1.f / (1024.f * 256.f);
#pragma unroll
    for (int u = 0; u < 4; ++u) {
        int t = tid + (u << 8);
        mv[(size_t)b * LL + t] = bufB[PHY(t)].x * sc;
    }
}

// ---------------- kernel 5: batch-mean over b, argmax/argmin over tau
__global__ __launch_bounds__(1024) void argidx_kernel(
    const float* __restrict__ mv, int* __restrict__ istats) {
    __shared__ float smax[1024], smin[1024];
    __shared__ int imax[1024], imin[1024];
    const int t = threadIdx.x;
    float g = 0.f;
    for (int b = 0; b < BB; ++b) g += mv[(size_t)b * LL + t];
    smax[t] = g; smin[t] = g; imax[t] = t; imin[t] = t;
    __syncthreads();
    for (int s = 512; s > 0; s >>= 1) {
        if (t < s) {
            if (smax[t + s] > smax[t] ||
                (smax[t + s] == smax[t] && imax[t + s] < imax[t])) {
                smax[t] = smax[t + s]; imax[t] = imax[t + s];
            }
            if (smin[t + s] < smin[t] ||
                (smin[t + s] == smin[t] && imin[t + s] > imin[t])) {
                smin[t] = smin[t + s]; imin[t] = imin[t + s];
            }
        }
        __syncthreads();
    }
    if (t == 0) { istats[0] = imax[0]; istats[1] = imin[0]; }
}

// ---------------- kernel 6: per-b softmax weights at idx0 / idx1
__global__ __launch_bounds__(256) void softmax_kernel(
    const float* __restrict__ mv, const int* __restrict__ istats,
    float* __restrict__ w01) {
    __shared__ float red[256];
    const int b = blockIdx.x, t = threadIdx.x;
    const float scale = 0.0625f;
    const float* row = mv + (size_t)b * LL;
    float m = -INFINITY;
    for (int i = t; i < LL; i += 256) m = fmaxf(m, row[i]);
    red[t] = m; __syncthreads();
    for (int s = 128; s > 0; s >>= 1) {
        if (t < s) red[t] = fmaxf(red[t], red[t + s]);
        __syncthreads();
    }
    m = red[0]; __syncthreads();
    float sum = 0.f;
    for (int i = t; i < LL; i += 256) sum += expf((row[i] - m) * scale);
    red[t] = sum; __syncthreads();
    for (int s = 128; s > 0; s >>= 1) {
        if (t < s) red[t] += red[t + s];
        __syncthreads();
    }
    if (t == 0) {
        float denom = red[0];
        w01[b]      = expf((row[istats[0]] - m) * scale) / denom;
        w01[BB + b] = expf((row[istats[1]] - m) * scale) / denom;
    }
}

// ---------------- kernel 7: gather rolled vsub columns, scale, write out
__global__ __launch_bounds__(256) void out_kernel(
    const float* __restrict__ vsub, const int* __restrict__ istats,
    const float* __restrict__ w01, float* __restrict__ out) {
    const int i = blockIdx.x * 256 + threadIdx.x;
    const int half = (i >= BB * LL * KK) ? 1 : 0;
    const int j = i - half * BB * LL * KK;
    const int b = j / (LL * KK);
    const int rem = j % (LL * KK);
    const int l = rem / KK, kk = rem % KK;
    const int sh = istats[half];
    const int lr = (l + sh) & (LL - 1);
    const float w = w01[half * BB + b];
    out[i] = vsub[(size_t)(b * LL + lr) * 16 + half * 8 + kk] * w;
}

extern "C" void kernel_launch(void* const* d_in, const int* in_sizes, int n_in,
                              void* d_out, int out_size, void* d_ws, size_t ws_size,
                              hipStream_t stream) {
    const float* S  = (const float*)d_in[0];
    const float* T  = (const float*)d_in[1];
    const float* Wq = (const float*)d_in[2];
    const float* Wk = (const float*)d_in[4];
    const float* Wv = (const float*)d_in[6];
    const float* bv = (const float*)d_in[7];

    float* ws    = (float*)d_ws;
    unsigned short* mhiT = (unsigned short*)(ws + O_MHI);
    unsigned short* mloT = (unsigned short*)(ws + O_MLO);
    float* bvaug = ws + O_BVAUG;
    unsigned short* thiT = (unsigned short*)(ws + O_X);
    unsigned short* tloT = (unsigned short*)(ws + O_X + 8388608);
    float* st    = ws + O_X;                  // aliases ThiT/TloT (after gemm)
    float* kp_t  = ws + O_KPT;
    float* vsub  = ws + O_VSUB;
    float* mv    = ws + O_MV;
    float* stats = ws + O_STATS;
    int*   istats = (int*)stats;
    float* w01    = stats + 8;

    build_maug<<<272, 256, 0, stream>>>(Wq, Wk, Wv, bv, mhiT, mloT, bvaug);
    split_T<<<(BB * LL * EE) / (256 * 8), 256, 0, stream>>>(T, thiT, tloT);
    gemm_mfma<<<(BB * LL) / 64, 256, 0, stream>>>(thiT, tloT, mhiT, mloT, bvaug, kp_t, vsub);
    dim3 gT(LL / 32, EE / 32, BB);
    transpose_S<<<gT, 256, 0, stream>>>(S, st);
    xcorr_kernel<<<BB * 32, 256, 0, stream>>>(st, kp_t);
    ifft_kernel<<<BB, 256, 0, stream>>>(st, mv);
    argidx_kernel<<<1, 1024, 0, stream>>>(mv, istats);
    softmax_kernel<<<BB, 256, 0, stream>>>(mv, istats, w01);
    out_kernel<<<(2 * BB * LL * KK) / 256, 256, 0, stream>>>(vsub, istats, w01, (float*)d_out);
}

// Round 9
// 166.317 us; speedup vs baseline: 1.1623x; 1.1623x over previous
//
#include <hip/hip_runtime.h>
#include <hip/hip_bf16.h>
#include <math.h>

#define BB 64
#define LL 1024
#define EE 256
#define KK 8
#define EPB 8        // e-channels per xcorr block
#define CHUNKS (EE/EPB)

typedef __attribute__((ext_vector_type(8))) short  bfrag;   // 8 bf16 (4 VGPRs)
typedef __attribute__((ext_vector_type(4))) short  short4v; // 4 bf16 (8B)
typedef __attribute__((ext_vector_type(4))) float  f32x4;

// Maug tiled: per kb (8): 320 rows x 32 k shorts (rows 272..319 pad) = 10240 shorts
#define MT_KB 10240

// workspace layout (units: floats)
#define O_MHI    ((size_t)0)                    // 8*10240 shorts = 40960 floats
#define O_MLO    ((size_t)40960)                // 40960
#define O_BVAUG  ((size_t)81920)                // 16 floats
#define O_X      ((size_t)81984)                // 16777216: ThiT+TloT (gemm), then St (fft)
#define O_KPT    (O_X + (size_t)16777216)       // B*E*L ([b][e][l])
#define O_VSUB   (O_KPT + (size_t)16777216)     // B*L*16 = 1048576
#define O_MV     (O_VSUB + (size_t)1048576)     // B*L = 65536
#define O_STATS  (O_MV + (size_t)65536)
// xcorr partials (513 float2 per (b,chunk)) overlay the head of each block's own
// St slab (slab = EPB*LL = 8192 floats >= 1026) — consumed by that block first.

__device__ __forceinline__ float2 cmulf(float2 a, float2 b) {
    return make_float2(a.x * b.x - a.y * b.y, a.x * b.y + a.y * b.x);
}

__device__ __forceinline__ int PHY(int i) { return i + (i >> 4); }  // LDS pad

__device__ __forceinline__ void splitbf(float x, unsigned short& h, unsigned short& l) {
    __hip_bfloat16 hb = __float2bfloat16(x);
    float hf = __bfloat162float(hb);
    __hip_bfloat16 lb = __float2bfloat16(x - hf);
    h = *(unsigned short*)&hb;
    l = *(unsigned short*)&lb;
}

__device__ __forceinline__ void gload16(const unsigned short* g, unsigned short* l) {
    __builtin_amdgcn_global_load_lds(
        (const __attribute__((address_space(1))) unsigned int*)g,
        (__attribute__((address_space(3))) unsigned int*)l, 16, 0, 0);
}

__device__ __forceinline__ int slot_of(int r, int kq) { return (kq + (r >> 1)) & 3; }

// ---------------- kernel 1: Maug = [Wq^T Wk ; Wv rows 0..7,248..255], bf16 hi/lo, tiled+swizzled
__global__ __launch_bounds__(256) void build_maug(
    const float* __restrict__ Wq, const float* __restrict__ Wk,
    const float* __restrict__ Wv, const float* __restrict__ bv,
    unsigned short* __restrict__ mhiT, unsigned short* __restrict__ mloT,
    float* __restrict__ bvaug) {
    int n = blockIdx.x;   // 0..271
    int j = threadIdx.x;  // k: 0..255
    float acc;
    if (n < EE) {
        acc = 0.f;
        for (int e = 0; e < EE; ++e)
            acc += Wq[e * EE + n] * Wk[e * EE + j];
    } else {
        int t = n - EE;
        int c = (t < 8) ? t : (240 + t);
        acc = Wv[c * EE + j];
    }
    unsigned short h, l;
    splitbf(acc, h, l);
    const int kb = j >> 5, kq = (j >> 3) & 3;
    const size_t dst = (size_t)kb * MT_KB + n * 32 + slot_of(n, kq) * 8 + (j & 7);
    mhiT[dst] = h;
    mloT[dst] = l;
    if (n == 0 && j < 16) bvaug[j] = bv[(j < 8) ? j : (240 + j)];
}

// ---------------- kernel 1c: split T -> bf16 hi/lo in tiled+swizzled layout
__global__ __launch_bounds__(256) void split_T(
    const float* __restrict__ T,
    unsigned short* __restrict__ thiT, unsigned short* __restrict__ tloT) {
    const size_t g = (size_t)blockIdx.x * 256 + threadIdx.x;
    const size_t i = g * 8;
    const int s = (int)(i >> 8), k = (int)(i & 255);
    const int kb = k >> 5, kq = (k >> 3) & 3;
    const int st = s >> 6, row = s & 63;
    f32x4 v0 = *(const f32x4*)&T[i];
    f32x4 v1 = *(const f32x4*)&T[i + 4];
    short4v h0, l0, h1, l1;
#pragma unroll
    for (int j = 0; j < 4; ++j) {
        unsigned short h, l;
        splitbf(v0[j], h, l); h0[j] = (short)h; l0[j] = (short)l;
        splitbf(v1[j], h, l); h1[j] = (short)h; l1[j] = (short)l;
    }
    const size_t dst = ((size_t)(st * 8 + kb)) * 2048 + row * 32 + slot_of(row, kq) * 8;
    *(short4v*)&thiT[dst] = h0; *(short4v*)&thiT[dst + 4] = h1;
    *(short4v*)&tloT[dst] = l0; *(short4v*)&tloT[dst + 4] = l1;
}

// ---------------- kernel 1b: St[b][e][l] = S[b][l][e]
__global__ __launch_bounds__(256) void transpose_S(
    const float* __restrict__ S, float* __restrict__ St) {
    __shared__ float tile[32][33];
    const int b = blockIdx.z;
    const int l0 = blockIdx.x * 32, e0 = blockIdx.y * 32;
    const int tx = threadIdx.x & 31, ty = threadIdx.x >> 5;
#pragma unroll
    for (int i = 0; i < 32; i += 8)
        tile[ty + i][tx] = S[((size_t)b * LL + l0 + ty + i) * EE + e0 + tx];
    __syncthreads();
#pragma unroll
    for (int i = 0; i < 32; i += 8)
        St[((size_t)b * EE + e0 + ty + i) * LL + l0 + tx] = tile[tx][ty + i];
}

// ---------------- kernel 2: MFMA GEMM (unchanged from R7)
__global__ __launch_bounds__(256, 3) void gemm_mfma(
    const unsigned short* __restrict__ thiT, const unsigned short* __restrict__ tloT,
    const unsigned short* __restrict__ mhiT, const unsigned short* __restrict__ mloT,
    const float* __restrict__ bvaug,
    float* __restrict__ kp_t, float* __restrict__ vsub) {
    __shared__ alignas(16) unsigned short Ah[2048];
    __shared__ alignas(16) unsigned short Al[2048];
    __shared__ alignas(16) unsigned short Bh[10240];
    __shared__ alignas(16) unsigned short Bl[10240];
    const int tid = threadIdx.x;
    const int w = tid >> 6, lane = tid & 63;
    const int lrow = lane & 15, lk = lane >> 4;
    const int st = blockIdx.x;
    const size_t s0 = (size_t)st * 64;
    const int bb = (int)(s0 >> 10), l0 = (int)(s0 & 1023);
    const int gl = w * 64 + lane;

    f32x4 acc[4][4];
    f32x4 acc2[4];
#pragma unroll
    for (int m = 0; m < 4; ++m) {
#pragma unroll
        for (int c = 0; c < 4; ++c) acc[m][c] = (f32x4){0.f, 0.f, 0.f, 0.f};
        acc2[m] = (f32x4){0.f, 0.f, 0.f, 0.f};
    }

    for (int kb = 0; kb < 8; ++kb) {
        __syncthreads();
        const unsigned short* asrcH = thiT + ((size_t)(st * 8 + kb)) * 2048;
        const unsigned short* asrcL = tloT + ((size_t)(st * 8 + kb)) * 2048;
        gload16(asrcH + gl * 8, &Ah[(size_t)w * 512]);
        gload16(asrcL + gl * 8, &Al[(size_t)w * 512]);
        const unsigned short* bsrcH = mhiT + (size_t)kb * MT_KB;
        const unsigned short* bsrcL = mloT + (size_t)kb * MT_KB;
#pragma unroll
        for (int q = 0; q < 5; ++q)
            gload16(bsrcH + q * 2048 + gl * 8, &Bh[q * 2048 + w * 512]);
#pragma unroll
        for (int q = 0; q < 5; ++q)
            gload16(bsrcL + q * 2048 + gl * 8, &Bl[q * 2048 + w * 512]);
        __syncthreads();

        bfrag ah[4], al[4];
#pragma unroll
        for (int m = 0; m < 4; ++m) {
            const int row = m * 16 + lrow;
            const int off = row * 32 + slot_of(row, lk) * 8;
            ah[m] = *(const bfrag*)&Ah[off];
            al[m] = *(const bfrag*)&Al[off];
        }
#pragma unroll
        for (int c = 0; c < 4; ++c) {
            const int n = w * 64 + c * 16 + lrow;
            const int off = n * 32 + slot_of(n, lk) * 8;
            bfrag bh = *(const bfrag*)&Bh[off];
            bfrag bl = *(const bfrag*)&Bl[off];
#pragma unroll
            for (int m = 0; m < 4; ++m) {
                acc[m][c] = __builtin_amdgcn_mfma_f32_16x16x32_bf16(ah[m], bh, acc[m][c], 0, 0, 0);
                acc[m][c] = __builtin_amdgcn_mfma_f32_16x16x32_bf16(ah[m], bl, acc[m][c], 0, 0, 0);
                acc[m][c] = __builtin_amdgcn_mfma_f32_16x16x32_bf16(al[m], bh, acc[m][c], 0, 0, 0);
            }
        }
        if (w == 0) {
            const int n = EE + lrow;
            const int off = n * 32 + slot_of(n, lk) * 8;
            bfrag bh = *(const bfrag*)&Bh[off];
            bfrag bl = *(const bfrag*)&Bl[off];
#pragma unroll
            for (int m = 0; m < 4; ++m) {
                acc2[m] = __builtin_amdgcn_mfma_f32_16x16x32_bf16(ah[m], bh, acc2[m], 0, 0, 0);
                acc2[m] = __builtin_amdgcn_mfma_f32_16x16x32_bf16(ah[m], bl, acc2[m], 0, 0, 0);
                acc2[m] = __builtin_amdgcn_mfma_f32_16x16x32_bf16(al[m], bh, acc2[m], 0, 0, 0);
            }
        }
    }
#pragma unroll
    for (int m = 0; m < 4; ++m) {
        const int srow = m * 16 + lk * 4;
#pragma unroll
        for (int c = 0; c < 4; ++c) {
            const int n = w * 64 + c * 16 + lrow;
            *(f32x4*)&kp_t[((size_t)(bb * EE + n)) * LL + l0 + srow] = acc[m][c];
        }
    }
    if (w == 0) {
        const float bvv = bvaug[lrow];
#pragma unroll
        for (int m = 0; m < 4; ++m) {
            const int srow = m * 16 + lk * 4;
#pragma unroll
            for (int j = 0; j < 4; ++j)
                vsub[(s0 + srow + j) * 16 + lrow] = acc2[m][j] + bvv;
        }
    }
}

// ---------------- radix-4 Stockham FFT, N=1024, 5 stages, 256 threads.
// Twiddles computed on the fly (no LDS table -> no bank-conflicted reads).
// Buffers PHY-padded (1088 float2). RESULT LANDS IN `b`.
template<bool INV>
__device__ __forceinline__ void fft1024_r4(float2* a, float2* b, int tid) {
    float2* src = a;
    float2* dst = b;
#pragma unroll
    for (int t = 0; t < 5; ++t) {
        const int Ns = 1 << (2 * t);     // 1,4,16,64,256
        __syncthreads();
        const int j = tid;
        const int k = j & (Ns - 1);
        // w1 = exp(-i*pi*k/(2Ns)); arg in (-pi/2, 0]
        float sv, cv;
        __sincosf(-3.14159265358979323846f * (float)k / (float)(2 * Ns), &sv, &cv);
        float2 w1 = make_float2(cv, sv);
        float2 w2 = cmulf(w1, w1);
        float2 w3 = cmulf(w1, w2);
        if (INV) { w1.y = -w1.y; w2.y = -w2.y; w3.y = -w3.y; }
        float2 a0 = src[PHY(j)];
        float2 a1 = cmulf(w1, src[PHY(j + 256)]);
        float2 a2 = cmulf(w2, src[PHY(j + 512)]);
        float2 a3 = cmulf(w3, src[PHY(j + 768)]);
        float2 t0 = make_float2(a0.x + a2.x, a0.y + a2.y);
        float2 t1 = make_float2(a0.x - a2.x, a0.y - a2.y);
        float2 t2 = make_float2(a1.x + a3.x, a1.y + a3.y);
        float2 t3 = make_float2(a1.x - a3.x, a1.y - a3.y);
        float2 u3 = INV ? make_float2(-t3.y, t3.x) : make_float2(t3.y, -t3.x);
        const int base = ((j >> (2 * t)) << (2 * t + 2)) + k;
        dst[PHY(base)]          = make_float2(t0.x + t2.x, t0.y + t2.y);
        dst[PHY(base + Ns)]     = make_float2(t1.x + u3.x, t1.y + u3.y);
        dst[PHY(base + 2 * Ns)] = make_float2(t0.x - t2.x, t0.y - t2.y);
        dst[PHY(base + 3 * Ns)] = make_float2(t1.x - u3.x, t1.y - u3.y);
        float2* tmp = src; src = dst; dst = tmp;
    }
    __syncthreads();
}

// ---------------- kernel 3: per (b, e-chunk): two-for-one FFT + cross-power partials
__global__ __launch_bounds__(256) void xcorr_kernel(
    float* __restrict__ St, const float* __restrict__ kp_t) {
    __shared__ float2 bufA[1088];
    __shared__ float2 bufB[1088];
    const int tid = threadIdx.x;
    const int b = blockIdx.x / CHUNKS;
    const int chunk = blockIdx.x % CHUNKS;

    float2 p0 = make_float2(0.f, 0.f);
    float2 p1 = make_float2(0.f, 0.f);
    float px2 = 0.f;                      // f=512 (lane 0 only)

    const size_t base = ((size_t)b * EE + (size_t)chunk * EPB) * LL;
    for (int ee = 0; ee < EPB; ++ee) {
        const size_t rbase = base + (size_t)ee * LL;
#pragma unroll
        for (int u = 0; u < 4; ++u) {
            int l = tid + (u << 8);
            bufA[PHY(l)] = make_float2(St[rbase + l], kp_t[rbase + l]);  // s + i*kp
        }
        fft1024_r4<false>(bufA, bufB, tid);   // result in bufB
        {
            float2 A = bufB[PHY(tid)];
            float2 C = bufB[PHY((1024 - tid) & 1023)];
            p0.x += 0.5f * (A.x * C.y + A.y * C.x);
            p0.y += 0.25f * ((A.x * A.x + A.y * A.y) - (C.x * C.x + C.y * C.y));
        }
        {
            int f = tid + 256;
            float2 A = bufB[PHY(f)];
            float2 C = bufB[PHY(1024 - f)];
            p1.x += 0.5f * (A.x * C.y + A.y * C.x);
            p1.y += 0.25f * ((A.x * A.x + A.y * A.y) - (C.x * C.x + C.y * C.y));
        }
        if (tid == 0) {
            float2 A = bufB[PHY(512)];
            px2 += A.x * A.y;
        }
    }
    float2* pp = (float2*)&St[base];      // own slab head (fully consumed above)
    pp[tid] = p0;
    pp[tid + 256] = p1;
    if (tid == 0) pp[512] = make_float2(px2, 0.f);
}

// ---------------- kernel 4: per b: reduce partials, Hermitian irfft -> mean_value
__global__ __launch_bounds__(256) void ifft_kernel(
    const float* __restrict__ St, float* __restrict__ mv) {
    __shared__ float2 bufA[1088];
    __shared__ float2 bufB[1088];
    const int tid = threadIdx.x;
    const int b = blockIdx.x;
#pragma unroll
    for (int u = 0; u < 2; ++u) {
        int f = tid + (u << 8);            // 0..511
        float2 s = make_float2(0.f, 0.f);
        for (int c = 0; c < CHUNKS; ++c) {
            const float2* pp = (const float2*)&St[((size_t)b * EE + (size_t)c * EPB) * LL];
            float2 v = pp[f];
            s.x += v.x; s.y += v.y;
        }
        if (f == 0) s.y = 0.f;
        bufA[PHY(f)] = s;
        if (f > 0) bufA[PHY(1024 - f)] = make_float2(s.x, -s.y);
    }
    if (tid == 0) {
        float sx = 0.f;
        for (int c = 0; c < CHUNKS; ++c) {
            const float2* pp = (const float2*)&St[((size_t)b * EE + (size_t)c * EPB) * LL];
            sx += pp[512].x;
        }
        bufA[PHY(512)] = make_float2(sx, 0.f);
    }
    fft1024_r4<true>(bufA, bufB, tid);
    const float sc = 1.f / (1024.f * 256.f);
#pragma unroll
    for (int u = 0; u < 4; ++u) {
        int t = tid + (u << 8);
        mv[(size_t)b * LL + t] = bufB[PHY(t)].x * sc;
    }
}

// ---------------- kernel 5: batch-mean over b, argmax/argmin over tau
__global__ __launch_bounds__(1024) void argidx_kernel(
    const float* __restrict__ mv, int* __restrict__ istats) {
    __shared__ float smax[1024], smin[1024];
    __shared__ int imax[1024], imin[1024];
    const int t = threadIdx.x;
    float g = 0.f;
    for (int b = 0; b < BB; ++b) g += mv[(size_t)b * LL + t];
    smax[t] = g; smin[t] = g; imax[t] = t; imin[t] = t;
    __syncthreads();
    for (int s = 512; s > 0; s >>= 1) {
        if (t < s) {
            if (smax[t + s] > smax[t] ||
                (smax[t + s] == smax[t] && imax[t + s] < imax[t])) {
                smax[t] = smax[t + s]; imax[t] = imax[t + s];
            }
            if (smin[t + s] < smin[t] ||
                (smin[t + s] == smin[t] && imin[t + s] > imin[t])) {
                smin[t] = smin[t + s]; imin[t] = imin[t + s];
            }
        }
        __syncthreads();
    }
    if (t == 0) { istats[0] = imax[0]; istats[1] = imin[0]; }
}

// ---------------- kernel 6: per-b softmax weights at idx0 / idx1
__global__ __launch_bounds__(256) void softmax_kernel(
    const float* __restrict__ mv, const int* __restrict__ istats,
    float* __restrict__ w01) {
    __shared__ float red[256];
    const int b = blockIdx.x, t = threadIdx.x;
    const float scale = 0.0625f;
    const float* row = mv + (size_t)b * LL;
    float m = -INFINITY;
    for (int i = t; i < LL; i += 256) m = fmaxf(m, row[i]);
    red[t] = m; __syncthreads();
    for (int s = 128; s > 0; s >>= 1) {
        if (t < s) red[t] = fmaxf(red[t], red[t + s]);
        __syncthreads();
    }
    m = red[0]; __syncthreads();
    float sum = 0.f;
    for (int i = t; i < LL; i += 256) sum += expf((row[i] - m) * scale);
    red[t] = sum; __syncthreads();
    for (int s = 128; s > 0; s >>= 1) {
        if (t < s) red[t] += red[t + s];
        __syncthreads();
    }
    if (t == 0) {
        float denom = red[0];
        w01[b]      = expf((row[istats[0]] - m) * scale) / denom;
        w01[BB + b] = expf((row[istats[1]] - m) * scale) / denom;
    }
}

// ---------------- kernel 7: gather rolled vsub columns, scale, write out
__global__ __launch_bounds__(256) void out_kernel(
    const float* __restrict__ vsub, const int* __restrict__ istats,
    const float* __restrict__ w01, float* __restrict__ out) {
    const int i = blockIdx.x * 256 + threadIdx.x;
    const int half = (i >= BB * LL * KK) ? 1 : 0;
    const int j = i - half * BB * LL * KK;
    const int b = j / (LL * KK);
    const int rem = j % (LL * KK);
    const int l = rem / KK, kk = rem % KK;
    const int sh = istats[half];
    const int lr = (l + sh) & (LL - 1);
    const float w = w01[half * BB + b];
    out[i] = vsub[(size_t)(b * LL + lr) * 16 + half * 8 + kk] * w;
}

extern "C" void kernel_launch(void* const* d_in, const int* in_sizes, int n_in,
                              void* d_out, int out_size, void* d_ws, size_t ws_size,
                              hipStream_t stream) {
    const float* S  = (const float*)d_in[0];
    const float* T  = (const float*)d_in[1];
    const float* Wq = (const float*)d_in[2];
    const float* Wk = (const float*)d_in[4];
    const float* Wv = (const float*)d_in[6];
    const float* bv = (const float*)d_in[7];

    float* ws    = (float*)d_ws;
    unsigned short* mhiT = (unsigned short*)(ws + O_MHI);
    unsigned short* mloT = (unsigned short*)(ws + O_MLO);
    float* bvaug = ws + O_BVAUG;
    unsigned short* thiT = (unsigned short*)(ws + O_X);
    unsigned short* tloT = (unsigned short*)(ws + O_X + 8388608);
    float* st    = ws + O_X;                  // aliases ThiT/TloT (after gemm)
    float* kp_t  = ws + O_KPT;
    float* vsub  = ws + O_VSUB;
    float* mv    = ws + O_MV;
    float* stats = ws + O_STATS;
    int*   istats = (int*)stats;
    float* w01    = stats + 8;

    build_maug<<<272, 256, 0, stream>>>(Wq, Wk, Wv, bv, mhiT, mloT, bvaug);
    split_T<<<(BB * LL * EE) / (256 * 8), 256, 0, stream>>>(T, thiT, tloT);
    gemm_mfma<<<(BB * LL) / 64, 256, 0, stream>>>(thiT, tloT, mhiT, mloT, bvaug, kp_t, vsub);
    dim3 gT(LL / 32, EE / 32, BB);
    transpose_S<<<gT, 256, 0, stream>>>(S, st);
    xcorr_kernel<<<BB * CHUNKS, 256, 0, stream>>>(st, kp_t);
    ifft_kernel<<<BB, 256, 0, stream>>>(st, mv);
    argidx_kernel<<<1, 1024, 0, stream>>>(mv, istats);
    softmax_kernel<<<BB, 256, 0, stream>>>(mv, istats, w01);
    out_kernel<<<(2 * BB * LL * KK) / 256, 256, 0, stream>>>(vsub, istats, w01, (float*)d_out);
}